// Round 11
// baseline (102.217 us; speedup 1.0000x reference)
//
#include <hip/hip_runtime.h>
#include <math.h>

// DSS layer via chunked state-space + MFMA (R11).
// y[32c+i] = D*u[32c+i] + sum_{j<=i} K[i-j]*u[32c+j]        (local Toeplitz, MFMA)
//          + Re( sum_n c_n z_n^{i+1} car_n(c) )             (carry response, MFMA)
// car_n(c+1) = z32_n*car_n(c) + s_n(c);  s_n(c) = sum_k z^{31-k} u[32c+k]  (S = Zf@U, MFMA)
// The 64-chunk carry recurrence keeps R10's verified Kogge-Stone (1/32 the work).
// Rationale: R2-R10 showed the scan pinned at the fp32-VALU throughput roofline
// (v_pk_fma_f32 = 2 pipe passes; clockmeter measured ~700 MHz effective clock).
// MFMA moves the O(L*N) work to the matrix pipe.
// Precision: bf16 hi/lo splits both operands, 3-term products (drop lo*lo).

static constexpr int kH = 1024;
static constexpr int kL = 2048;
static constexpr int kN = 32;
static constexpr float kEps = 1e-7f;

typedef __attribute__((ext_vector_type(8))) short s8;   // 8 bf16 (A/B frag)
typedef __attribute__((ext_vector_type(4))) float f4;   // C/D frag

__device__ __forceinline__ unsigned short f2bf(float x) {
    union { float f; unsigned u; } v; v.f = x;
    return (unsigned short)((v.u + 0x7fffu + ((v.u >> 16) & 1u)) >> 16);
}
__device__ __forceinline__ float bf2f(unsigned short b) {
    union { unsigned u; float f; } v; v.u = ((unsigned)b) << 16; return v.f;
}
// fragment tables: 10 tables, each [kH][2 tiles][64 lanes][8] bf16 (ushort units)
__device__ __forceinline__ size_t TBL(int t, int h, int q, int lane) {
    return ((((size_t)t * kH + h) * 2 + q) * 64 + (size_t)lane) * 8;
}

// ---------------- setup: bake zc + fragment tables ----------------
// block = 256 = 8 channels x 32; grid = kH/8
__global__ void dss_setup(const float* __restrict__ W,
                          const float* __restrict__ Lam,
                          const float* __restrict__ logstep,
                          float* __restrict__ zc,
                          unsigned short* __restrict__ fb) {
    __shared__ float K_s[8][32];
    __shared__ float zc_s[8][32][4];
    const int tid = threadIdx.x;
    const int chl = tid >> 5;
    const int h = blockIdx.x * 8 + chl;
    const int n = tid & 31;
    K_s[chl][n] = 0.f;
    __syncthreads();

    // ---- S1 per (h,n): z, c, powers z^0..z^31, K partials, Zf frags ----
    float step = expf(logstep[h]);
    float lr = Lam[2*n], li = Lam[2*n+1];
    float wr = W[((size_t)h*kN+n)*2], wi = W[((size_t)h*kN+n)*2+1];
    float ar = step*lr, ai = step*li;
    float ea = expf(ar); float sb, cb; sincosf(ai, &sb, &cb);
    float zr = ea*cb, zi = ea*sb;
    float em = expm1f(ar); float shh = sinf(0.5f*ai);
    float dr = fmaf(-em, cb, 2.f*shh*shh), di = -ea*sb;     // 1 - z (safe)
    float eL = expf(ar*(float)kL); float sL, cL; sincosf(ai*(float)kL, &sL, &cL);
    float nr = 1.f - eL*cL, ni = -eL*sL;                     // 1 - z^L
    float dd = dr*dr + di*di, id = 1.f/dd;
    float sr = (nr*dr + ni*di)*id, si = (ni*dr - nr*di)*id;  // s
    float ll = lr*lr + li*li, il = 1.f/ll;
    float qr = (wr*lr + wi*li)*il, qi = (wi*lr - wr*li)*il;  // w/lambda
    float ssq = fmaf(sr,sr, fmaf(si,si,kEps)); float is = 1.f/ssq;
    float cr = (qr*sr + qi*si)*is, ci = (qi*sr - qr*si)*is;  // c

    s8 zrh[4], zrl[4], zih[4], zil[4];
    float pr = 1.f, pi = 0.f;                                // z^e
#pragma unroll
    for (int e = 0; e < 32; ++e) {
        const int k = 31 - e, g = k >> 3, j = k & 7;         // Zf[n][k] = z^{31-k}
        unsigned short hr = f2bf(pr);
        zrh[g][j] = (short)hr; zrl[g][j] = (short)f2bf(pr - bf2f(hr));
        unsigned short hi_ = f2bf(pi);
        zih[g][j] = (short)hi_; zil[g][j] = (short)f2bf(pi - bf2f(hi_));
        atomicAdd(&K_s[chl][e], fmaf(cr, pr, -ci*pi));       // K[e] += Re(c z^e)
        float t = fmaf(pr, zr, -pi*zi);
        pi = fmaf(pr, zi, pi*zr);
        pr = t;
    }
    // zc: [0..3]=z,c  [4,5]=z^32 (exact from power chain)
    float* o = zc + ((size_t)h*kN + n)*8;
    o[0]=zr; o[1]=zi; o[2]=cr; o[3]=ci; o[4]=pr; o[5]=pi; o[6]=0.f; o[7]=0.f;
    zc_s[chl][n][0]=zr; zc_s[chl][n][1]=zi; zc_s[chl][n][2]=cr; zc_s[chl][n][3]=ci;
    {
        const int mb = n >> 4, rl = n & 15;
#pragma unroll
        for (int g = 0; g < 4; ++g) {
            *(s8*)(fb + TBL(0,h,mb,rl+16*g)) = zrh[g];
            *(s8*)(fb + TBL(1,h,mb,rl+16*g)) = zrl[g];
            *(s8*)(fb + TBL(2,h,mb,rl+16*g)) = zih[g];
            *(s8*)(fb + TBL(3,h,mb,rl+16*g)) = zil[g];
        }
    }
    __syncthreads();

    // ---- S2 per (h,i): R[i][n] = c_n z_n^{i+1} frags; T[i][j] = K[i-j] frags ----
    const int i = n;
    s8 rrh[4], rrl[4], rnh[4], rnl[4];
#pragma unroll
    for (int m = 0; m < 32; ++m) {
        const float bzr = zc_s[chl][m][0], bzi = zc_s[chl][m][1];
        const float bcr = zc_s[chl][m][2], bci = zc_s[chl][m][3];
        float ppr = 1.f, ppi = 0.f, br = bzr, bi = bzi;      // z^(i+1), binary exp
        const int e = i + 1;
#pragma unroll
        for (int b = 0; b < 6; ++b) {
            if ((e >> b) & 1) {
                float t = fmaf(ppr, br, -ppi*bi);
                ppi = fmaf(ppr, bi, ppi*br); ppr = t;
            }
            float t2 = fmaf(br, br, -bi*bi); bi = 2.f*br*bi; br = t2;
        }
        const float Rre = fmaf(bcr, ppr, -bci*ppi);
        const float Rni = -fmaf(bcr, ppi, bci*ppr);          // minus Im baked
        const int g = m >> 3, j = m & 7;
        unsigned short h1 = f2bf(Rre); rrh[g][j] = (short)h1; rrl[g][j] = (short)f2bf(Rre - bf2f(h1));
        unsigned short h2 = f2bf(Rni); rnh[g][j] = (short)h2; rnl[g][j] = (short)f2bf(Rni - bf2f(h2));
    }
    const int ib = i >> 4, rl2 = i & 15;
#pragma unroll
    for (int g = 0; g < 4; ++g) {
        *(s8*)(fb + TBL(4,h,ib,rl2+16*g)) = rrh[g];
        *(s8*)(fb + TBL(5,h,ib,rl2+16*g)) = rrl[g];
        *(s8*)(fb + TBL(6,h,ib,rl2+16*g)) = rnh[g];
        *(s8*)(fb + TBL(7,h,ib,rl2+16*g)) = rnl[g];
    }
    s8 th[4], tl[4];
#pragma unroll
    for (int j = 0; j < 32; ++j) {
        const float kv = (j <= i) ? K_s[chl][i - j] : 0.f;   // LDS runtime idx: fine
        unsigned short hv = f2bf(kv);
        th[j>>3][j&7] = (short)hv; tl[j>>3][j&7] = (short)f2bf(kv - bf2f(hv));
    }
#pragma unroll
    for (int g = 0; g < 4; ++g) {
        *(s8*)(fb + TBL(8,h,ib,rl2+16*g)) = th[g];
        *(s8*)(fb + TBL(9,h,ib,rl2+16*g)) = tl[g];
    }
}

// ---------------- main: MFMA S-build -> carry scan -> MFMA output ----------------
// block = 256 = 4 waves per channel; wave w owns chunk-block w (16 chunks).
__global__ __launch_bounds__(256)
void dss_main(const float* __restrict__ u,
              const float* __restrict__ zc,
              const unsigned short* __restrict__ fb,
              const float* __restrict__ Dv,
              float* __restrict__ y) {
    __shared__ float SL[64][66];      // S exchange; later aliased as ylds[64][34]
    __shared__ float CarL[64][68];
    const int h = blockIdx.x;
    const int tid = threadIdx.x;
    const int wv = tid >> 6;
    const int lane = tid & 63;
    const int cl = lane & 15;         // MFMA col = local chunk
    const int hq = lane >> 4;
    const int c = 16*wv + cl;         // global chunk for stages A/C

    // ---- u as B-frag: lane holds u[32c + 8*hq + j], j=0..7 ----
    const float* ug = u + (size_t)h*kL;
    float uu[8];
    {
        const f4 a0 = *(const f4*)(ug + 32*c + 8*hq);
        const f4 a1 = *(const f4*)(ug + 32*c + 8*hq + 4);
        uu[0]=a0.x; uu[1]=a0.y; uu[2]=a0.z; uu[3]=a0.w;
        uu[4]=a1.x; uu[5]=a1.y; uu[6]=a1.z; uu[7]=a1.w;
    }
    s8 Uh, Ul;
#pragma unroll
    for (int j = 0; j < 8; ++j) {
        unsigned short hv = f2bf(uu[j]);
        Uh[j] = (short)hv; Ul[j] = (short)f2bf(uu[j] - bf2f(hv));
    }

    // ---- Stage A: S = Zf @ U (complex re/im, hi/lo 3-term) ----
    f4 Sre[2] = {{0.f,0.f,0.f,0.f},{0.f,0.f,0.f,0.f}};
    f4 Sim[2] = {{0.f,0.f,0.f,0.f},{0.f,0.f,0.f,0.f}};
#pragma unroll
    for (int mb = 0; mb < 2; ++mb) {
        s8 a0 = *(const s8*)(fb + TBL(0,h,mb,lane));
        s8 a1 = *(const s8*)(fb + TBL(1,h,mb,lane));
        s8 a2 = *(const s8*)(fb + TBL(2,h,mb,lane));
        s8 a3 = *(const s8*)(fb + TBL(3,h,mb,lane));
        Sre[mb] = __builtin_amdgcn_mfma_f32_16x16x32_bf16(a0, Uh, Sre[mb], 0,0,0);
        Sre[mb] = __builtin_amdgcn_mfma_f32_16x16x32_bf16(a0, Ul, Sre[mb], 0,0,0);
        Sre[mb] = __builtin_amdgcn_mfma_f32_16x16x32_bf16(a1, Uh, Sre[mb], 0,0,0);
        Sim[mb] = __builtin_amdgcn_mfma_f32_16x16x32_bf16(a2, Uh, Sim[mb], 0,0,0);
        Sim[mb] = __builtin_amdgcn_mfma_f32_16x16x32_bf16(a2, Ul, Sim[mb], 0,0,0);
        Sim[mb] = __builtin_amdgcn_mfma_f32_16x16x32_bf16(a3, Uh, Sim[mb], 0,0,0);
    }
    // D-frag: col=lane&15 (chunk), row=(lane>>4)*4+r (mode-local)
#pragma unroll
    for (int mb = 0; mb < 2; ++mb)
#pragma unroll
        for (int r = 0; r < 4; ++r) {
            const int mode = 16*mb + 4*hq + r;
            *(float2*)&SL[c][2*mode] = make_float2(Sre[mb][r], Sim[mb][r]);
        }
    __syncthreads();

    // ---- Stage B: exclusive carry scan over 64 chunks (R10's verified KS) ----
    // wave wv owns modes 8wv..8wv+7; lane = chunk 0..63
    float Xr[8], Xi[8];
#pragma unroll
    for (int q = 0; q < 8; ++q) {
        float2 v = *(const float2*)&SL[lane][16*wv + 2*q];
        Xr[q] = v.x; Xi[q] = v.y;
    }
#pragma unroll
    for (int q = 0; q < 8; ++q) {
        float vr = __shfl_up(Xr[q], 1), vi = __shfl_up(Xi[q], 1);
        Xr[q] = (lane >= 1) ? vr : 0.f;
        Xi[q] = (lane >= 1) ? vi : 0.f;
    }
    const int wvu = __builtin_amdgcn_readfirstlane(wv);
    const float* zch = zc + ((size_t)h*kN + 8*wvu)*8;
    float pr[8], pi[8];
#pragma unroll
    for (int q = 0; q < 8; ++q) { pr[q] = zch[q*8+4]; pi[q] = zch[q*8+5]; }
#pragma unroll 1
    for (int d = 1; d < 64; d <<= 1) {
#pragma unroll
        for (int q = 0; q < 8; ++q) {
            float vr = __shfl_up(Xr[q], d), vi = __shfl_up(Xi[q], d);
            const bool ok = lane >= d;
            vr = ok ? vr : 0.f; vi = ok ? vi : 0.f;
            Xr[q] = fmaf(pr[q], vr, fmaf(-pi[q], vi, Xr[q]));
            Xi[q] = fmaf(pr[q], vi, fmaf(pi[q], vr, Xi[q]));
        }
#pragma unroll
        for (int q = 0; q < 8; ++q) {
            float t = fmaf(pr[q], pr[q], -pi[q]*pi[q]);
            pi[q] = 2.f*pr[q]*pi[q]; pr[q] = t;
        }
    }
    // carries into chunk `lane` -> CarL[chunk][2*mode + ri]
#pragma unroll
    for (int v2 = 0; v2 < 4; ++v2) {
        *(f4*)&CarL[lane][16*wvu + 4*v2] =
            (f4){Xr[2*v2], Xi[2*v2], Xr[2*v2+1], Xi[2*v2+1]};
    }
    __syncthreads();

    // ---- Stage C: acc = T@U + Rre@CarRe + (-Rim)@CarIm ----
    s8 Crh, Crl, Cih, Cil;
#pragma unroll
    for (int v2 = 0; v2 < 4; ++v2) {
        const f4 cv = *(const f4*)&CarL[c][16*hq + 4*v2];
        unsigned short t1 = f2bf(cv.x); Crh[2*v2]   = (short)t1; Crl[2*v2]   = (short)f2bf(cv.x - bf2f(t1));
        unsigned short t2 = f2bf(cv.z); Crh[2*v2+1] = (short)t2; Crl[2*v2+1] = (short)f2bf(cv.z - bf2f(t2));
        unsigned short t3 = f2bf(cv.y); Cih[2*v2]   = (short)t3; Cil[2*v2]   = (short)f2bf(cv.y - bf2f(t3));
        unsigned short t4 = f2bf(cv.w); Cih[2*v2+1] = (short)t4; Cil[2*v2+1] = (short)f2bf(cv.w - bf2f(t4));
    }
    f4 acc[2] = {{0.f,0.f,0.f,0.f},{0.f,0.f,0.f,0.f}};
#pragma unroll
    for (int ib = 0; ib < 2; ++ib) {
        s8 t0 = *(const s8*)(fb + TBL(8,h,ib,lane));
        s8 t1 = *(const s8*)(fb + TBL(9,h,ib,lane));
        acc[ib] = __builtin_amdgcn_mfma_f32_16x16x32_bf16(t0, Uh, acc[ib], 0,0,0);
        acc[ib] = __builtin_amdgcn_mfma_f32_16x16x32_bf16(t0, Ul, acc[ib], 0,0,0);
        acc[ib] = __builtin_amdgcn_mfma_f32_16x16x32_bf16(t1, Uh, acc[ib], 0,0,0);
        s8 r0 = *(const s8*)(fb + TBL(4,h,ib,lane));
        s8 r1 = *(const s8*)(fb + TBL(5,h,ib,lane));
        s8 r2 = *(const s8*)(fb + TBL(6,h,ib,lane));
        s8 r3 = *(const s8*)(fb + TBL(7,h,ib,lane));
        acc[ib] = __builtin_amdgcn_mfma_f32_16x16x32_bf16(r0, Crh, acc[ib], 0,0,0);
        acc[ib] = __builtin_amdgcn_mfma_f32_16x16x32_bf16(r0, Crl, acc[ib], 0,0,0);
        acc[ib] = __builtin_amdgcn_mfma_f32_16x16x32_bf16(r1, Crh, acc[ib], 0,0,0);
        acc[ib] = __builtin_amdgcn_mfma_f32_16x16x32_bf16(r2, Cih, acc[ib], 0,0,0);
        acc[ib] = __builtin_amdgcn_mfma_f32_16x16x32_bf16(r2, Cil, acc[ib], 0,0,0);
        acc[ib] = __builtin_amdgcn_mfma_f32_16x16x32_bf16(r3, Cih, acc[ib], 0,0,0);
    }
    // ylds aliases SL (all SL reads completed before previous barrier)
    float* yl = &SL[0][0];
#pragma unroll
    for (int ib = 0; ib < 2; ++ib)
#pragma unroll
        for (int r = 0; r < 4; ++r) {
            yl[c*34 + 16*ib + 4*hq + r] = acc[ib][r];   // y-index i = 16ib+4hq+r
        }
    __syncthreads();

    // ---- epilogue: y = D*u + ylds, coalesced ----
    const float Dh = Dv[h];
    float* yg = y + (size_t)h*kL;
    for (int e = tid; e < kL; e += 256) {
        yg[e] = fmaf(Dh, ug[e], yl[(e >> 5)*34 + (e & 31)]);
    }
}

extern "C" void kernel_launch(void* const* d_in, const int* in_sizes, int n_in,
                              void* d_out, int out_size, void* d_ws, size_t ws_size,
                              hipStream_t stream) {
    const float* u        = (const float*)d_in[0];  // (H, L)
    const float* W        = (const float*)d_in[1];  // (H, N, 2)
    const float* Lam      = (const float*)d_in[2];  // (N, 2)
    const float* log_step = (const float*)d_in[3];  // (H,)
    const float* Dv       = (const float*)d_in[4];  // (H,)
    float* y  = (float*)d_out;                      // (H, L) fp32
    float* zc = (float*)d_ws;                       // [kH][kN][8] f32 = 1 MB
    unsigned short* fb = (unsigned short*)(zc + (size_t)kH*kN*8);  // 10 x 2 MB tables

    dss_setup<<<kH/8, 256, 0, stream>>>(W, Lam, log_step, zc, fb);
    dss_main<<<kH, 256, 0, stream>>>(u, zc, fb, Dv, y);
}

// Round 12
// 81.027 us; speedup vs baseline: 1.2615x; 1.2615x over previous
//
#include <hip/hip_runtime.h>
#include <math.h>

// DSS layer, fully fused chunked state-space + MFMA (R12).
// Per channel h (one block, 256 thr = 4 waves):
//   0a) powers z_n^0..32 -> LDS p[32][33]; c_n -> LDS  (parallel, no atomics)
//   0b) K[e] = sum_n Re(c_n z_n^e) -> LDS (shfl-tree reduce)
//   A)  S = Zf @ U per 16-chunk tile (MFMA, hi/lo bf16 3-term)
//   B)  64-chunk Kogge-Stone carry scan (fp32 VALU, 1/32 of old scan work)
//   C)  y = T@U + Rre@CarRe + Rni@CarIm (MFMA), + D*u epilogue
// R11 verified the fragment layouts + numerics (absmax identical to fp32
// path); R12 removes R11's regressions: setup kernel with 32-way
// same-address LDS atomics, 20 MB fragment-table HBM round-trip, 2nd launch.

static constexpr int kH = 1024;
static constexpr int kL = 2048;
static constexpr int kN = 32;
static constexpr float kEps = 1e-7f;

typedef __attribute__((ext_vector_type(8))) short s8;   // 8 bf16 (A/B frag)
typedef __attribute__((ext_vector_type(4))) float f4;   // C/D frag

__device__ __forceinline__ unsigned short f2bf(float x) {
    union { float f; unsigned u; } v; v.f = x;
    return (unsigned short)((v.u + 0x7fffu + ((v.u >> 16) & 1u)) >> 16);
}
__device__ __forceinline__ float bf2f(unsigned short b) {
    union { unsigned u; float f; } v; v.u = ((unsigned)b) << 16; return v.f;
}

#define MFMA __builtin_amdgcn_mfma_f32_16x16x32_bf16

__global__ __launch_bounds__(256)
void dss_fused(const float* __restrict__ u,
               const float* __restrict__ W,
               const float* __restrict__ Lam,
               const float* __restrict__ logstep,
               const float* __restrict__ Dv,
               float* __restrict__ y) {
    __shared__ float pre[kN][33];     // Re z^e, e=0..32
    __shared__ float pim[kN][33];     // Im z^e
    __shared__ float ccs[kN][2];      // c_n
    __shared__ float Kk[kN];          // K[e]
    __shared__ float SL[64][66];      // S exchange; later aliased as y staging
    __shared__ float CarL[64][68];    // carry exchange

    const int h = blockIdx.x;
    const int tid = threadIdx.x;
    const int wv = tid >> 6, lane = tid & 63;
    const int cl = lane & 15, hq = lane >> 4;
    const int c = 16 * wv + cl;       // this lane's chunk (stages A/C)

    // ---------- 0a: z-powers and c_n ----------
    {
        const int n = tid >> 3, g = tid & 7;   // 32 modes x 8 power-groups
        const float step = expf(logstep[h]);
        const float lr = Lam[2*n], li = Lam[2*n+1];
        const float ar = step * lr, ai = step * li;
        const float ea = expf(ar);
        float sb, cb; sincosf(ai, &sb, &cb);
        const float zr = ea * cb, zi = ea * sb;
        // z^4
        const float t2r = fmaf(zr, zr, -zi*zi), t2i = 2.f*zr*zi;
        const float z4r = fmaf(t2r, t2r, -t2i*t2i), z4i = 2.f*t2r*t2i;
        // q = (z^4)^g, 3-bit binexp
        float qr = 1.f, qi = 0.f, br = z4r, bi = z4i;
#pragma unroll
        for (int b = 0; b < 3; ++b) {
            if ((g >> b) & 1) {
                const float t = fmaf(qr, br, -qi*bi);
                qi = fmaf(qr, bi, qi*br); qr = t;
            }
            const float t = fmaf(br, br, -bi*bi);
            bi = 2.f*br*bi; br = t;
        }
        float cr_ = qr, ci_ = qi;                 // z^{4g}
        pre[n][4*g] = cr_; pim[n][4*g] = ci_;
#pragma unroll
        for (int t = 1; t < 4; ++t) {
            const float nr2 = fmaf(cr_, zr, -ci_*zi);
            ci_ = fmaf(cr_, zi, ci_*zr); cr_ = nr2;
            pre[n][4*g+t] = cr_; pim[n][4*g+t] = ci_;
        }
        if (g == 7) {                             // z^32
            const float nr2 = fmaf(cr_, zr, -ci_*zi);
            ci_ = fmaf(cr_, zi, ci_*zr); cr_ = nr2;
            pre[n][32] = cr_; pim[n][32] = ci_;
        }
        if (g == 0) {                             // c_n closed form
            const float wr = W[((size_t)h*kN+n)*2], wi = W[((size_t)h*kN+n)*2+1];
            const float em = expm1f(ar);
            const float sh = sinf(0.5f*ai);
            const float dr = fmaf(-em, cb, 2.f*sh*sh), di = -ea*sb;  // 1-z safe
            const float eL = expf(ar*(float)kL);
            float sL, cL2; sincosf(ai*(float)kL, &sL, &cL2);
            const float nrr = 1.f - eL*cL2, nii = -eL*sL;            // 1-z^L
            const float dd = dr*dr + di*di, id = 1.f/dd;
            const float srr = (nrr*dr + nii*di)*id, sii = (nii*dr - nrr*di)*id;
            const float ll = lr*lr + li*li, il = 1.f/ll;
            const float qrr = (wr*lr + wi*li)*il, qii = (wi*lr - wr*li)*il;
            const float ssq = fmaf(srr, srr, fmaf(sii, sii, kEps));
            const float is = 1.f/ssq;
            ccs[n][0] = (qrr*srr + qii*sii)*is;
            ccs[n][1] = (qii*srr - qrr*sii)*is;
        }
    }
    __syncthreads();

    // ---------- 0b: K[e] via shfl-tree ----------
    {
        const int e = tid >> 3, g = tid & 7;
        float acc = 0.f;
#pragma unroll
        for (int t = 0; t < 4; ++t) {
            const int n = 4*g + t;
            acc = fmaf(ccs[n][0], pre[n][e], acc);
            acc = fmaf(-ccs[n][1], pim[n][e], acc);
        }
        acc += __shfl_down(acc, 4);
        acc += __shfl_down(acc, 2);
        acc += __shfl_down(acc, 1);
        if (g == 0) Kk[e] = acc;
    }
    __syncthreads();

    // ---------- u as B-frag (hi/lo bf16) ----------
    const float* ug = u + (size_t)h * kL;
    s8 Uh, Ul;
    {
        const f4 a0 = *(const f4*)(ug + 32*c + 8*hq);
        const f4 a1 = *(const f4*)(ug + 32*c + 8*hq + 4);
        const float uu[8] = {a0.x,a0.y,a0.z,a0.w, a1.x,a1.y,a1.z,a1.w};
#pragma unroll
        for (int j = 0; j < 8; ++j) {
            const unsigned short hv = f2bf(uu[j]);
            Uh[j] = (short)hv; Ul[j] = (short)f2bf(uu[j] - bf2f(hv));
        }
    }

    // ---------- Stage A: S = Zf @ U ----------
    f4 Sre[2] = {{0.f,0.f,0.f,0.f},{0.f,0.f,0.f,0.f}};
    f4 Sim[2] = {{0.f,0.f,0.f,0.f},{0.f,0.f,0.f,0.f}};
#pragma unroll
    for (int mb = 0; mb < 2; ++mb) {
        const int n = cl + 16*mb;                 // A-row = mode
        s8 a0, a1, a2, a3;
#pragma unroll
        for (int j = 0; j < 8; ++j) {
            const int e = 31 - (8*hq + j);        // Zf[n][k] = z^{31-k}
            const float vr = pre[n][e], vi = pim[n][e];
            const unsigned short h1 = f2bf(vr);
            a0[j] = (short)h1; a1[j] = (short)f2bf(vr - bf2f(h1));
            const unsigned short h2 = f2bf(vi);
            a2[j] = (short)h2; a3[j] = (short)f2bf(vi - bf2f(h2));
        }
        Sre[mb] = MFMA(a0, Uh, Sre[mb], 0,0,0);
        Sre[mb] = MFMA(a0, Ul, Sre[mb], 0,0,0);
        Sre[mb] = MFMA(a1, Uh, Sre[mb], 0,0,0);
        Sim[mb] = MFMA(a2, Uh, Sim[mb], 0,0,0);
        Sim[mb] = MFMA(a2, Ul, Sim[mb], 0,0,0);
        Sim[mb] = MFMA(a3, Uh, Sim[mb], 0,0,0);
    }
#pragma unroll
    for (int mb = 0; mb < 2; ++mb)
#pragma unroll
        for (int r = 0; r < 4; ++r) {
            const int mode = 16*mb + 4*hq + r;    // D-row = mode
            *(float2*)&SL[c][2*mode] = make_float2(Sre[mb][r], Sim[mb][r]);
        }
    __syncthreads();

    // ---------- Stage B: 64-chunk Kogge-Stone carry scan ----------
    float Xr[8], Xi[8];
#pragma unroll
    for (int q = 0; q < 8; ++q) {
        const float2 v = *(const float2*)&SL[lane][16*wv + 2*q];
        Xr[q] = v.x; Xi[q] = v.y;
    }
#pragma unroll
    for (int q = 0; q < 8; ++q) {
        const float vr = __shfl_up(Xr[q], 1), vi = __shfl_up(Xi[q], 1);
        Xr[q] = (lane >= 1) ? vr : 0.f;
        Xi[q] = (lane >= 1) ? vi : 0.f;
    }
    float prq[8], piq[8];
#pragma unroll
    for (int q = 0; q < 8; ++q) {                 // ratio z^32 from LDS, once
        prq[q] = pre[8*wv + q][32];
        piq[q] = pim[8*wv + q][32];
        asm volatile("" : "+v"(prq[q]), "+v"(piq[q]));  // pin: no LDS re-reads
    }
#pragma unroll 1
    for (int d = 1; d < 64; d <<= 1) {
#pragma unroll
        for (int q = 0; q < 8; ++q) {
            float vr = __shfl_up(Xr[q], d), vi = __shfl_up(Xi[q], d);
            const bool ok = lane >= d;
            vr = ok ? vr : 0.f; vi = ok ? vi : 0.f;
            Xr[q] = fmaf(prq[q], vr, fmaf(-piq[q], vi, Xr[q]));
            Xi[q] = fmaf(prq[q], vi, fmaf(piq[q], vr, Xi[q]));
        }
#pragma unroll
        for (int q = 0; q < 8; ++q) {
            const float t = fmaf(prq[q], prq[q], -piq[q]*piq[q]);
            piq[q] = 2.f*prq[q]*piq[q]; prq[q] = t;
        }
    }
    const int wvu = __builtin_amdgcn_readfirstlane(wv);
#pragma unroll
    for (int v2 = 0; v2 < 4; ++v2) {
        *(f4*)&CarL[lane][16*wvu + 4*v2] =
            (f4){Xr[2*v2], Xi[2*v2], Xr[2*v2+1], Xi[2*v2+1]};
    }
    __syncthreads();

    // ---------- Stage C: y = T@U + Rre@CarRe + Rni@CarIm ----------
    s8 Crh, Crl, Cih, Cil;
#pragma unroll
    for (int v2 = 0; v2 < 4; ++v2) {
        const f4 cv = *(const f4*)&CarL[c][16*hq + 4*v2];
        const unsigned short t1 = f2bf(cv.x);
        Crh[2*v2]   = (short)t1; Crl[2*v2]   = (short)f2bf(cv.x - bf2f(t1));
        const unsigned short t2 = f2bf(cv.z);
        Crh[2*v2+1] = (short)t2; Crl[2*v2+1] = (short)f2bf(cv.z - bf2f(t2));
        const unsigned short t3 = f2bf(cv.y);
        Cih[2*v2]   = (short)t3; Cil[2*v2]   = (short)f2bf(cv.y - bf2f(t3));
        const unsigned short t4 = f2bf(cv.w);
        Cih[2*v2+1] = (short)t4; Cil[2*v2+1] = (short)f2bf(cv.w - bf2f(t4));
    }
    float* yl = &SL[0][0];                        // alias SL (reads all done)
#pragma unroll
    for (int ib = 0; ib < 2; ++ib) {
        const int i = cl + 16*ib;                 // A-row = output elem
        s8 th_, tl_, r0, r1, r2, r3;
#pragma unroll
        for (int jj = 0; jj < 8; ++jj) {
            const int j = 8*hq + jj;              // A-col (k)
            const float kv = (j <= i) ? Kk[i - j] : 0.f;
            const unsigned short hv = f2bf(kv);
            th_[jj] = (short)hv; tl_[jj] = (short)f2bf(kv - bf2f(hv));
            const int m = j;                      // mode for R
            const float pr_ = pre[m][i+1], pi_ = pim[m][i+1];
            const float crm = ccs[m][0], cim = ccs[m][1];
            const float Rre = fmaf(crm, pr_, -cim*pi_);
            const float Rni = -fmaf(crm, pi_, cim*pr_);
            const unsigned short h1 = f2bf(Rre);
            r0[jj] = (short)h1; r1[jj] = (short)f2bf(Rre - bf2f(h1));
            const unsigned short h2 = f2bf(Rni);
            r2[jj] = (short)h2; r3[jj] = (short)f2bf(Rni - bf2f(h2));
        }
        f4 acc = {0.f,0.f,0.f,0.f};
        acc = MFMA(th_, Uh, acc, 0,0,0);
        acc = MFMA(th_, Ul, acc, 0,0,0);
        acc = MFMA(tl_, Uh, acc, 0,0,0);
        acc = MFMA(r0, Crh, acc, 0,0,0);
        acc = MFMA(r0, Crl, acc, 0,0,0);
        acc = MFMA(r1, Crh, acc, 0,0,0);
        acc = MFMA(r2, Cih, acc, 0,0,0);
        acc = MFMA(r2, Cil, acc, 0,0,0);
        acc = MFMA(r3, Cih, acc, 0,0,0);
#pragma unroll
        for (int r = 0; r < 4; ++r) {
            yl[c*34 + 16*ib + 4*hq + r] = acc[r]; // D-row = 4*hq+r
        }
    }
    __syncthreads();

    // ---------- epilogue: y = D*u + staged, coalesced ----------
    const float Dh = Dv[h];
    float* yg = y + (size_t)h * kL;
    for (int e = tid; e < kL; e += 256) {
        yg[e] = fmaf(Dh, ug[e], yl[(e >> 5)*34 + (e & 31)]);
    }
}

extern "C" void kernel_launch(void* const* d_in, const int* in_sizes, int n_in,
                              void* d_out, int out_size, void* d_ws, size_t ws_size,
                              hipStream_t stream) {
    const float* u        = (const float*)d_in[0];  // (H, L)
    const float* W        = (const float*)d_in[1];  // (H, N, 2)
    const float* Lam      = (const float*)d_in[2];  // (N, 2)
    const float* log_step = (const float*)d_in[3];  // (H,)
    const float* Dv       = (const float*)d_in[4];  // (H,)
    float* y = (float*)d_out;                       // (H, L) fp32

    dss_fused<<<kH, 256, 0, stream>>>(u, W, Lam, log_step, Dv, y);
}